// Round 1
// baseline (1748.173 us; speedup 1.0000x reference)
//
#include <hip/hip_runtime.h>
#include <math.h>

#define N_USERS 40000
#define N_ITEMS 20000
#define NNODES  60000          // N_USERS + N_ITEMS
#define D       128
#define N_EDGES 320000
#define LAYERS  3
#define EPS_    1e-7f
#define BATCH   4096

// ---- degree count: deg[node] += 1 per incident directed edge -------------
__global__ void deg_count(const int* __restrict__ au, const int* __restrict__ ai,
                          float* __restrict__ deg) {
    int e = blockIdx.x * blockDim.x + threadIdx.x;
    if (e >= N_EDGES) return;
    atomicAdd(&deg[au[e]], 1.0f);
    atomicAdd(&deg[N_USERS + ai[e]], 1.0f);
}

// ---- dinv[i] = (deg[i] + eps)^-1/2, in place ------------------------------
__global__ void make_dinv(float* __restrict__ deg) {
    int i = blockIdx.x * blockDim.x + threadIdx.x;
    if (i >= NNODES) return;
    deg[i] = rsqrtf(deg[i] + EPS_);
}

// ---- x = acc = concat(user_emb, item_emb), float4-vectorized --------------
__global__ void init_x(const float4* __restrict__ ue, const float4* __restrict__ ie,
                       float4* __restrict__ x, float4* __restrict__ acc) {
    const int NU4 = N_USERS * D / 4;
    const int NT4 = NNODES * D / 4;
    int i = blockIdx.x * blockDim.x + threadIdx.x;
    if (i >= NT4) return;
    float4 v = (i < NU4) ? ue[i] : ie[i - NU4];
    x[i] = v;
    acc[i] = v;
}

// ---- SpMM scatter: out[r] += dinv[r]*dinv[c] * x[c], one wave per edge ----
// Directed edges: e < N_EDGES -> (user, item); else reversed.
__global__ void spmm_scatter(const int* __restrict__ au, const int* __restrict__ ai,
                             const float* __restrict__ dinv,
                             const float* __restrict__ x, float* __restrict__ out) {
    int gw   = (blockIdx.x * blockDim.x + threadIdx.x) >> 6;  // global wave id
    int lane = threadIdx.x & 63;
    if (gw >= 2 * N_EDGES) return;
    int r, c;
    if (gw < N_EDGES) { r = au[gw];                 c = N_USERS + ai[gw]; }
    else              { int e = gw - N_EDGES; r = N_USERS + ai[e]; c = au[e]; }
    float v = dinv[r] * dinv[c];
    const float2* xc = (const float2*)(x + (size_t)c * D);
    float2 t = xc[lane];                       // coalesced 512B per wave
    float* orow = out + (size_t)r * D + 2 * lane;
    atomicAdd(orow,     v * t.x);
    atomicAdd(orow + 1, v * t.y);
}

// ---- acc += x_next --------------------------------------------------------
__global__ void acc_add(const float4* __restrict__ xn, float4* __restrict__ acc) {
    const int NT4 = NNODES * D / 4;
    int i = blockIdx.x * blockDim.x + threadIdx.x;
    if (i >= NT4) return;
    float4 a = acc[i], b = xn[i];
    a.x += b.x; a.y += b.y; a.z += b.z; a.w += b.w;
    acc[i] = a;
}

// ---- BPR loss: one wave per batch element, block-reduced atomic ----------
// all_emb = acc/4, so score diff = (acc_u.acc_p - acc_u.acc_n) / 16
__global__ void bpr_loss(const float* __restrict__ acc,
                         const int* __restrict__ user, const int* __restrict__ pos,
                         const int* __restrict__ neg, float* __restrict__ lacc) {
    __shared__ float s[4];
    int gw   = (blockIdx.x * blockDim.x + threadIdx.x) >> 6;
    int lane = threadIdx.x & 63;
    int wv   = threadIdx.x >> 6;
    float ls = 0.0f;
    if (gw < BATCH) {
        int u = user[gw];
        int p = N_USERS + pos[gw] - 1;   // 1-indexed items
        int n = N_USERS + neg[gw] - 1;
        const float2* tu = (const float2*)(acc + (size_t)u * D);
        const float2* pi = (const float2*)(acc + (size_t)p * D);
        const float2* ni = (const float2*)(acc + (size_t)n * D);
        float2 a = tu[lane], b = pi[lane], c = ni[lane];
        float sp = a.x * b.x + a.y * b.y;
        float sn = a.x * c.x + a.y * c.y;
        #pragma unroll
        for (int off = 32; off; off >>= 1) {
            sp += __shfl_down(sp, off);
            sn += __shfl_down(sn, off);
        }
        if (lane == 0) {
            float diff = (sp - sn) * (1.0f / 16.0f);
            // log_sigmoid(x) = min(x,0) - log1p(exp(-|x|))
            ls = fminf(diff, 0.0f) - log1pf(expf(-fabsf(diff)));
        }
    }
    if (lane == 0) s[wv] = ls;
    __syncthreads();
    if (threadIdx.x == 0) atomicAdd(lacc, s[0] + s[1] + s[2] + s[3]);
}

__global__ void finalize(const float* __restrict__ lacc, float* __restrict__ out) {
    out[0] = -lacc[0] * (1.0f / (float)BATCH);
}

extern "C" void kernel_launch(void* const* d_in, const int* in_sizes, int n_in,
                              void* d_out, int out_size, void* d_ws, size_t ws_size,
                              hipStream_t stream) {
    const float* ue  = (const float*)d_in[0];
    const float* ie  = (const float*)d_in[1];
    const int*   au  = (const int*)d_in[2];
    const int*   ai  = (const int*)d_in[3];
    const int*   usr = (const int*)d_in[4];
    const int*   pos = (const int*)d_in[5];
    const int*   neg = (const int*)d_in[6];
    float*       out = (float*)d_out;

    // workspace layout (floats): dinv[60000] | xa[7.68M] | xb[7.68M] | acc[7.68M] | lacc[1]
    float* ws   = (float*)d_ws;
    float* dinv = ws;
    float* xa   = ws + NNODES;                    // 240000 B offset, 16B-aligned
    float* xb   = xa + (size_t)NNODES * D;
    float* acc  = xb + (size_t)NNODES * D;
    float* lacc = acc + (size_t)NNODES * D;

    const size_t xbytes = (size_t)NNODES * D * sizeof(float);
    const int NT4 = NNODES * D / 4;

    hipMemsetAsync(dinv, 0, NNODES * sizeof(float), stream);
    hipMemsetAsync(lacc, 0, sizeof(float), stream);

    deg_count<<<(N_EDGES + 255) / 256, 256, 0, stream>>>(au, ai, dinv);
    make_dinv<<<(NNODES + 255) / 256, 256, 0, stream>>>(dinv);
    init_x<<<(NT4 + 255) / 256, 256, 0, stream>>>((const float4*)ue, (const float4*)ie,
                                                  (float4*)xa, (float4*)acc);

    float* cur = xa;
    float* nxt = xb;
    for (int l = 0; l < LAYERS; ++l) {
        hipMemsetAsync(nxt, 0, xbytes, stream);
        // 2*N_EDGES waves, 4 waves (256 threads) per block
        spmm_scatter<<<(2 * N_EDGES) / 4, 256, 0, stream>>>(au, ai, dinv, cur, nxt);
        acc_add<<<(NT4 + 255) / 256, 256, 0, stream>>>((const float4*)nxt, (float4*)acc);
        float* t = cur; cur = nxt; nxt = t;
    }

    bpr_loss<<<BATCH / 4, 256, 0, stream>>>(acc, usr, pos, neg, lacc);
    finalize<<<1, 1, 0, stream>>>(lacc, out);
}

// Round 2
// 463.984 us; speedup vs baseline: 3.7677x; 3.7677x over previous
//
#include <hip/hip_runtime.h>
#include <math.h>

#define N_USERS 40000
#define N_ITEMS 20000
#define NNODES  60000          // N_USERS + N_ITEMS
#define D       128
#define N_EDGES 320000
#define NDIR    (2 * N_EDGES)  // directed edges
#define LAYERS  3
#define EPS_    1e-7f
#define BATCH   4096

// ---- degree count (int): cnt[r] += 1 per directed edge -------------------
__global__ void deg_count(const int* __restrict__ au, const int* __restrict__ ai,
                          int* __restrict__ cnt) {
    int e = blockIdx.x * blockDim.x + threadIdx.x;
    if (e >= N_EDGES) return;
    atomicAdd(&cnt[au[e]], 1);
    atomicAdd(&cnt[N_USERS + ai[e]], 1);
}

// ---- dinv[i] = (cnt[i] + eps)^-1/2 ---------------------------------------
__global__ void make_dinv(const int* __restrict__ cnt, float* __restrict__ dinv) {
    int i = blockIdx.x * blockDim.x + threadIdx.x;
    if (i >= NNODES) return;
    dinv[i] = rsqrtf((float)cnt[i] + EPS_);
}

// ---- exclusive scan of cnt[NNODES] -> base[NNODES+1], single block -------
__global__ void scan_csr(const int* __restrict__ cnt, int* __restrict__ base) {
    __shared__ int s[1024];
    const int CH = (NNODES + 1023) / 1024;   // 59
    int t  = threadIdx.x;
    int lo = t * CH;
    int hi = lo + CH; if (hi > NNODES) hi = NNODES;
    int sum = 0;
    for (int i = lo; i < hi; ++i) sum += cnt[i];
    s[t] = sum;
    __syncthreads();
    // inclusive Hillis-Steele scan over 1024 partials
    for (int off = 1; off < 1024; off <<= 1) {
        int v = (t >= off) ? s[t - off] : 0;
        __syncthreads();
        s[t] += v;
        __syncthreads();
    }
    int run = (t == 0) ? 0 : s[t - 1];
    for (int i = lo; i < hi; ++i) { base[i] = run; run += cnt[i]; }
    if (t == 1023) base[NNODES] = s[1023];
}

// ---- CSR fill: col[base[r] + fill[r]++] = c ------------------------------
__global__ void fill_csr(const int* __restrict__ au, const int* __restrict__ ai,
                         const int* __restrict__ base, int* __restrict__ fillc,
                         int* __restrict__ col) {
    int e = blockIdx.x * blockDim.x + threadIdx.x;
    if (e >= NDIR) return;
    int r, c;
    if (e < N_EDGES) { r = au[e];                  c = N_USERS + ai[e]; }
    else             { int k = e - N_EDGES; r = N_USERS + ai[k]; c = au[k]; }
    int pos = base[r] + atomicAdd(&fillc[r], 1);
    col[pos] = c;
}

// ---- x = acc = concat(user_emb, item_emb) --------------------------------
__global__ void init_x(const float4* __restrict__ ue, const float4* __restrict__ ie,
                       float4* __restrict__ x, float4* __restrict__ acc) {
    const int NU4 = N_USERS * D / 4;
    const int NT4 = NNODES * D / 4;
    int i = blockIdx.x * blockDim.x + threadIdx.x;
    if (i >= NT4) return;
    float4 v = (i < NU4) ? ue[i] : ie[i - NU4];
    x[i] = v;
    acc[i] = v;
}

// ---- SpMM gather (fused acc +=): one wave per row ------------------------
// nxt[r] = dinv[r] * sum_{c in N(r)} dinv[c] * x[c];  acc[r] += nxt[r]
__global__ void spmm_gather(const int* __restrict__ base, const int* __restrict__ col,
                            const float* __restrict__ dinv,
                            const float* __restrict__ x,
                            float* __restrict__ nxt, float* __restrict__ acc) {
    int gw   = (blockIdx.x * blockDim.x + threadIdx.x) >> 6;  // row
    int lane = threadIdx.x & 63;
    if (gw >= NNODES) return;
    int s = base[gw], e = base[gw + 1];
    float2 sum0 = make_float2(0.f, 0.f);
    float2 sum1 = make_float2(0.f, 0.f);
    int j = s;
    for (; j + 1 < e; j += 2) {
        int c0 = col[j], c1 = col[j + 1];
        float w0 = dinv[c0], w1 = dinv[c1];
        const float2* x0 = (const float2*)(x + (size_t)c0 * D);
        const float2* x1 = (const float2*)(x + (size_t)c1 * D);
        float2 t0 = x0[lane], t1 = x1[lane];
        sum0.x += w0 * t0.x; sum0.y += w0 * t0.y;
        sum1.x += w1 * t1.x; sum1.y += w1 * t1.y;
    }
    if (j < e) {
        int c0 = col[j];
        float w0 = dinv[c0];
        const float2* x0 = (const float2*)(x + (size_t)c0 * D);
        float2 t0 = x0[lane];
        sum0.x += w0 * t0.x; sum0.y += w0 * t0.y;
    }
    float wr = dinv[gw];
    float2 y = make_float2(wr * (sum0.x + sum1.x), wr * (sum0.y + sum1.y));
    float2* nrow = (float2*)(nxt + (size_t)gw * D);
    float2* arow = (float2*)(acc + (size_t)gw * D);
    nrow[lane] = y;
    float2 a = arow[lane];
    a.x += y.x; a.y += y.y;
    arow[lane] = a;
}

// ---- BPR loss: one wave per batch element, block-reduced atomic ----------
// all_emb = acc/4, so score diff = (acc_u.acc_p - acc_u.acc_n) / 16
__global__ void bpr_loss(const float* __restrict__ acc,
                         const int* __restrict__ user, const int* __restrict__ pos,
                         const int* __restrict__ neg, float* __restrict__ lacc) {
    __shared__ float s[4];
    int gw   = (blockIdx.x * blockDim.x + threadIdx.x) >> 6;
    int lane = threadIdx.x & 63;
    int wv   = threadIdx.x >> 6;
    float ls = 0.0f;
    if (gw < BATCH) {
        int u = user[gw];
        int p = N_USERS + pos[gw] - 1;   // 1-indexed items
        int n = N_USERS + neg[gw] - 1;
        const float2* tu = (const float2*)(acc + (size_t)u * D);
        const float2* pi = (const float2*)(acc + (size_t)p * D);
        const float2* ni = (const float2*)(acc + (size_t)n * D);
        float2 a = tu[lane], b = pi[lane], c = ni[lane];
        float sp = a.x * b.x + a.y * b.y;
        float sn = a.x * c.x + a.y * c.y;
        #pragma unroll
        for (int off = 32; off; off >>= 1) {
            sp += __shfl_down(sp, off);
            sn += __shfl_down(sn, off);
        }
        if (lane == 0) {
            float diff = (sp - sn) * (1.0f / 16.0f);
            // log_sigmoid(x) = min(x,0) - log1p(exp(-|x|))
            ls = fminf(diff, 0.0f) - log1pf(expf(-fabsf(diff)));
        }
    }
    if (lane == 0) s[wv] = ls;
    __syncthreads();
    if (threadIdx.x == 0) atomicAdd(lacc, s[0] + s[1] + s[2] + s[3]);
}

__global__ void finalize(const float* __restrict__ lacc, float* __restrict__ out) {
    out[0] = -lacc[0] * (1.0f / (float)BATCH);
}

extern "C" void kernel_launch(void* const* d_in, const int* in_sizes, int n_in,
                              void* d_out, int out_size, void* d_ws, size_t ws_size,
                              hipStream_t stream) {
    const float* ue  = (const float*)d_in[0];
    const float* ie  = (const float*)d_in[1];
    const int*   au  = (const int*)d_in[2];
    const int*   ai  = (const int*)d_in[3];
    const int*   usr = (const int*)d_in[4];
    const int*   pos = (const int*)d_in[5];
    const int*   neg = (const int*)d_in[6];
    float*       out = (float*)d_out;

    const size_t XN = (size_t)NNODES * D;   // 7,680,000 floats

    // workspace layout (16B-aligned chunks):
    // xa | xb | acc | dinv[60000] | cnt[60000] | base[60008] | fillc[60000] | col[640000] | lacc
    float* xa    = (float*)d_ws;
    float* xb    = xa + XN;
    float* acc   = xb + XN;
    float* dinv  = acc + XN;
    int*   cnt   = (int*)(dinv + NNODES);
    int*   base  = cnt + NNODES;
    int*   fillc = base + 60008;            // NNODES+1 rounded up, keeps 16B align
    int*   col   = fillc + NNODES;
    float* lacc  = (float*)(col + NDIR);

    const int NT4 = NNODES * D / 4;

    hipMemsetAsync(cnt,   0, NNODES * sizeof(int), stream);
    hipMemsetAsync(fillc, 0, NNODES * sizeof(int), stream);
    hipMemsetAsync(lacc,  0, sizeof(float), stream);

    deg_count<<<(N_EDGES + 255) / 256, 256, 0, stream>>>(au, ai, cnt);
    make_dinv<<<(NNODES + 255) / 256, 256, 0, stream>>>(cnt, dinv);
    scan_csr<<<1, 1024, 0, stream>>>(cnt, base);
    fill_csr<<<(NDIR + 255) / 256, 256, 0, stream>>>(au, ai, base, fillc, col);
    init_x<<<(NT4 + 255) / 256, 256, 0, stream>>>((const float4*)ue, (const float4*)ie,
                                                  (float4*)xa, (float4*)acc);

    float* cur = xa;
    float* nxt = xb;
    for (int l = 0; l < LAYERS; ++l) {
        // one wave per row, 4 waves per block
        spmm_gather<<<(NNODES + 3) / 4, 256, 0, stream>>>(base, col, dinv, cur, nxt, acc);
        float* t = cur; cur = nxt; nxt = t;
    }

    bpr_loss<<<BATCH / 4, 256, 0, stream>>>(acc, usr, pos, neg, lacc);
    finalize<<<1, 1, 0, stream>>>(lacc, out);
}

// Round 3
// 383.228 us; speedup vs baseline: 4.5617x; 1.2107x over previous
//
#include <hip/hip_runtime.h>
#include <math.h>

#define N_USERS 40000
#define N_ITEMS 20000
#define NNODES  60000          // N_USERS + N_ITEMS
#define D       128
#define N_EDGES 320000
#define NDIR    (2 * N_EDGES)  // directed edges
#define LAYERS  3
#define EPS_    1e-7f
#define BATCH   4096
#define NBLK    ((NNODES + 255) / 256)   // 235 scan blocks

// ---- degree count (int): cnt[r] += 1 per directed edge -------------------
__global__ void deg_count(const int* __restrict__ au, const int* __restrict__ ai,
                          int* __restrict__ cnt) {
    int e = blockIdx.x * blockDim.x + threadIdx.x;
    if (e >= N_EDGES) return;
    atomicAdd(&cnt[au[e]], 1);
    atomicAdd(&cnt[N_USERS + ai[e]], 1);
}

// ---- dinv[i] = (cnt[i]+eps)^-1/2 ; dinv2 = dinv^2 ------------------------
__global__ void make_dinv(const int* __restrict__ cnt, float* __restrict__ dinv,
                          float* __restrict__ dinv2) {
    int i = blockIdx.x * blockDim.x + threadIdx.x;
    if (i >= NNODES) return;
    float w = rsqrtf((float)cnt[i] + EPS_);
    dinv[i] = w;
    dinv2[i] = w * w;
}

// ---- hierarchical exclusive scan: 235-block reduce / top scan / block scan
__global__ void blk_reduce(const int* __restrict__ cnt, int* __restrict__ bsum) {
    int idx = blockIdx.x * 256 + threadIdx.x;
    int v = (idx < NNODES) ? cnt[idx] : 0;
    #pragma unroll
    for (int off = 32; off; off >>= 1) v += __shfl_down(v, off);
    __shared__ int s[4];
    if ((threadIdx.x & 63) == 0) s[threadIdx.x >> 6] = v;
    __syncthreads();
    if (threadIdx.x == 0) bsum[blockIdx.x] = s[0] + s[1] + s[2] + s[3];
}

__global__ void scan_tops(const int* __restrict__ bsum, int* __restrict__ boff) {
    __shared__ int s[256];
    int t = threadIdx.x;
    int v = (t < NBLK) ? bsum[t] : 0;
    s[t] = v;
    __syncthreads();
    for (int off = 1; off < 256; off <<= 1) {
        int u = (t >= off) ? s[t - off] : 0;
        __syncthreads();
        s[t] += u;
        __syncthreads();
    }
    if (t < NBLK) boff[t] = s[t] - v;   // exclusive of block sums
}

__global__ void blk_scan(const int* __restrict__ cnt, const int* __restrict__ boff,
                         int* __restrict__ base) {
    __shared__ int s[256];
    int t = threadIdx.x;
    int idx = blockIdx.x * 256 + t;
    int v = (idx < NNODES) ? cnt[idx] : 0;
    s[t] = v;
    __syncthreads();
    for (int off = 1; off < 256; off <<= 1) {
        int u = (t >= off) ? s[t - off] : 0;
        __syncthreads();
        s[t] += u;
        __syncthreads();
    }
    if (idx < NNODES) base[idx] = boff[blockIdx.x] + s[t] - v;  // exclusive
    if (idx == 0) base[NNODES] = NDIR;
}

// ---- CSR fill: col[base[r] + fill[r]++] = c ------------------------------
__global__ void fill_csr(const int* __restrict__ au, const int* __restrict__ ai,
                         const int* __restrict__ base, int* __restrict__ fillc,
                         int* __restrict__ col) {
    int e = blockIdx.x * blockDim.x + threadIdx.x;
    if (e >= NDIR) return;
    int r, c;
    if (e < N_EDGES) { r = au[e];                  c = N_USERS + ai[e]; }
    else             { int k = e - N_EDGES; r = N_USERS + ai[k]; c = au[k]; }
    int pos = base[r] + atomicAdd(&fillc[r], 1);
    col[pos] = c;
}

// ---- z = zacc = dinv[row] * concat(user_emb, item_emb) -------------------
__global__ void init_z(const float4* __restrict__ ue, const float4* __restrict__ ie,
                       const float* __restrict__ dinv,
                       float4* __restrict__ z, float4* __restrict__ zacc) {
    const int NU4 = N_USERS * D / 4;
    const int NT4 = NNODES * D / 4;
    int i = blockIdx.x * blockDim.x + threadIdx.x;
    if (i >= NT4) return;
    float4 v = (i < NU4) ? ue[i] : ie[i - NU4];
    float w = dinv[i >> 5];          // D/4 = 32 float4 per row
    v.x *= w; v.y *= w; v.z *= w; v.w *= w;
    z[i] = v;
    zacc[i] = v;
}

// ---- SpMM gather in z-space (fused acc), one wave per row ----------------
// znxt[r] = dinv2[r] * sum_{c in N(r)} z[c];  zacc[r] += znxt[r]
__global__ void spmm_gather(const int* __restrict__ base, const int* __restrict__ col,
                            const float* __restrict__ dinv2,
                            const float* __restrict__ z,
                            float* __restrict__ znxt, float* __restrict__ zacc) {
    int row  = (blockIdx.x * blockDim.x + threadIdx.x) >> 6;
    int lane = threadIdx.x & 63;
    if (row >= NNODES) return;
    int s = base[row], e = base[row + 1];
    float2 s0 = make_float2(0.f, 0.f);
    float2 s1 = make_float2(0.f, 0.f);
    int j = s;
    for (; j + 1 < e; j += 2) {
        int c0 = col[j], c1 = col[j + 1];
        const float2* p0 = (const float2*)(z + (size_t)c0 * D);
        const float2* p1 = (const float2*)(z + (size_t)c1 * D);
        float2 t0 = p0[lane], t1 = p1[lane];
        s0.x += t0.x; s0.y += t0.y;
        s1.x += t1.x; s1.y += t1.y;
    }
    if (j < e) {
        int c0 = col[j];
        const float2* p0 = (const float2*)(z + (size_t)c0 * D);
        float2 t0 = p0[lane];
        s0.x += t0.x; s0.y += t0.y;
    }
    float w = dinv2[row];
    float2 y = make_float2(w * (s0.x + s1.x), w * (s0.y + s1.y));
    ((float2*)(znxt + (size_t)row * D))[lane] = y;
    float2* ar = (float2*)(zacc + (size_t)row * D);
    float2 a = ar[lane];
    a.x += y.x; a.y += y.y;
    ar[lane] = a;
}

// ---- BPR loss on z-space acc: unscale after the dot reduction ------------
// x_acc = zacc/dinv; all_emb = x_acc/4 => diff = (sp/(du*dp) - sn/(du*dn))/16
__global__ void bpr_loss(const float* __restrict__ zacc, const float* __restrict__ dinv,
                         const int* __restrict__ user, const int* __restrict__ pos,
                         const int* __restrict__ neg, float* __restrict__ lacc) {
    __shared__ float s[4];
    int gw   = (blockIdx.x * blockDim.x + threadIdx.x) >> 6;
    int lane = threadIdx.x & 63;
    int wv   = threadIdx.x >> 6;
    float ls = 0.0f;
    if (gw < BATCH) {
        int u = user[gw];
        int p = N_USERS + pos[gw] - 1;   // 1-indexed items
        int n = N_USERS + neg[gw] - 1;
        const float2* tu = (const float2*)(zacc + (size_t)u * D);
        const float2* pi = (const float2*)(zacc + (size_t)p * D);
        const float2* ni = (const float2*)(zacc + (size_t)n * D);
        float2 a = tu[lane], b = pi[lane], c = ni[lane];
        float sp = a.x * b.x + a.y * b.y;
        float sn = a.x * c.x + a.y * c.y;
        #pragma unroll
        for (int off = 32; off; off >>= 1) {
            sp += __shfl_down(sp, off);
            sn += __shfl_down(sn, off);
        }
        if (lane == 0) {
            float du = dinv[u], dp = dinv[p], dn = dinv[n];
            float diff = (sp / (du * dp) - sn / (du * dn)) * (1.0f / 16.0f);
            // log_sigmoid(x) = min(x,0) - log1p(exp(-|x|))
            ls = fminf(diff, 0.0f) - log1pf(expf(-fabsf(diff)));
        }
    }
    if (lane == 0) s[wv] = ls;
    __syncthreads();
    if (threadIdx.x == 0) atomicAdd(lacc, s[0] + s[1] + s[2] + s[3]);
}

__global__ void finalize(const float* __restrict__ lacc, float* __restrict__ out) {
    out[0] = -lacc[0] * (1.0f / (float)BATCH);
}

extern "C" void kernel_launch(void* const* d_in, const int* in_sizes, int n_in,
                              void* d_out, int out_size, void* d_ws, size_t ws_size,
                              hipStream_t stream) {
    const float* ue  = (const float*)d_in[0];
    const float* ie  = (const float*)d_in[1];
    const int*   au  = (const int*)d_in[2];
    const int*   ai  = (const int*)d_in[3];
    const int*   usr = (const int*)d_in[4];
    const int*   pos = (const int*)d_in[5];
    const int*   neg = (const int*)d_in[6];
    float*       out = (float*)d_out;

    const size_t XN = (size_t)NNODES * D;   // 7,680,000 floats

    // ws layout: za | zb | zacc | dinv | dinv2 | cnt | base[60008] | fillc |
    //            col[640000] | bsum[256] | boff[256] | lacc
    float* za    = (float*)d_ws;
    float* zb    = za + XN;
    float* zacc  = zb + XN;
    float* dinv  = zacc + XN;
    float* dinv2 = dinv + NNODES;
    int*   cnt   = (int*)(dinv2 + NNODES);
    int*   base  = cnt + NNODES;
    int*   fillc = base + 60008;            // NNODES+1 rounded up, keeps 16B align
    int*   col   = fillc + NNODES;
    int*   bsum  = col + NDIR;
    int*   boff  = bsum + 256;
    float* lacc  = (float*)(boff + 256);

    const int NT4 = NNODES * D / 4;

    hipMemsetAsync(cnt,   0, NNODES * sizeof(int), stream);
    hipMemsetAsync(fillc, 0, NNODES * sizeof(int), stream);
    hipMemsetAsync(lacc,  0, sizeof(float), stream);

    deg_count<<<(N_EDGES + 255) / 256, 256, 0, stream>>>(au, ai, cnt);
    make_dinv<<<(NNODES + 255) / 256, 256, 0, stream>>>(cnt, dinv, dinv2);
    blk_reduce<<<NBLK, 256, 0, stream>>>(cnt, bsum);
    scan_tops<<<1, 256, 0, stream>>>(bsum, boff);
    blk_scan<<<NBLK, 256, 0, stream>>>(cnt, boff, base);
    fill_csr<<<(NDIR + 255) / 256, 256, 0, stream>>>(au, ai, base, fillc, col);
    init_z<<<(NT4 + 255) / 256, 256, 0, stream>>>((const float4*)ue, (const float4*)ie,
                                                  dinv, (float4*)za, (float4*)zacc);

    float* cur = za;
    float* nxt = zb;
    for (int l = 0; l < LAYERS; ++l) {
        spmm_gather<<<(NNODES + 3) / 4, 256, 0, stream>>>(base, col, dinv2, cur, nxt, zacc);
        float* t = cur; cur = nxt; nxt = t;
    }

    bpr_loss<<<BATCH / 4, 256, 0, stream>>>(zacc, dinv, usr, pos, neg, lacc);
    finalize<<<1, 1, 0, stream>>>(lacc, out);
}

// Round 4
// 287.270 us; speedup vs baseline: 6.0855x; 1.3340x over previous
//
#include <hip/hip_runtime.h>
#include <math.h>

#define N_USERS 40000
#define N_ITEMS 20000
#define NNODES  60000          // N_USERS + N_ITEMS
#define D       128
#define N_EDGES 320000
#define NDIR    (2 * N_EDGES)  // directed edges
#define LAYERS  3
#define EPS_    1e-7f
#define BATCH   4096
#define NBLK    ((NNODES + 255) / 256)   // 235 scan blocks

__device__ __forceinline__ unsigned bf16x2_pack(float a, float b) {
    // round-to-nearest-even f32 -> bf16, packed low/high
    unsigned ua = __float_as_uint(a);
    unsigned ub = __float_as_uint(b);
    ua = (ua + 0x7FFF + ((ua >> 16) & 1)) >> 16;
    ub = (ub + 0x7FFF + ((ub >> 16) & 1)) >> 16;
    return ua | (ub << 16);
}
__device__ __forceinline__ float bf16_lo(unsigned p) { return __uint_as_float(p << 16); }
__device__ __forceinline__ float bf16_hi(unsigned p) { return __uint_as_float(p & 0xFFFF0000u); }

// ---- degree count (int): cnt[r] += 1 per directed edge -------------------
__global__ void deg_count(const int* __restrict__ au, const int* __restrict__ ai,
                          int* __restrict__ cnt) {
    int e = blockIdx.x * blockDim.x + threadIdx.x;
    if (e >= N_EDGES) return;
    atomicAdd(&cnt[au[e]], 1);
    atomicAdd(&cnt[N_USERS + ai[e]], 1);
}

// ---- fused: per-block sum of cnt + dinv/dinv2 ----------------------------
__global__ void blk_reduce(const int* __restrict__ cnt, int* __restrict__ bsum,
                           float* __restrict__ dinv, float* __restrict__ dinv2) {
    int idx = blockIdx.x * 256 + threadIdx.x;
    int v = 0;
    if (idx < NNODES) {
        v = cnt[idx];
        float w = rsqrtf((float)v + EPS_);
        dinv[idx] = w;
        dinv2[idx] = w * w;
    }
    int r = v;
    #pragma unroll
    for (int off = 32; off; off >>= 1) r += __shfl_down(r, off);
    __shared__ int s[4];
    if ((threadIdx.x & 63) == 0) s[threadIdx.x >> 6] = r;
    __syncthreads();
    if (threadIdx.x == 0) bsum[blockIdx.x] = s[0] + s[1] + s[2] + s[3];
}

__global__ void scan_tops(const int* __restrict__ bsum, int* __restrict__ boff) {
    __shared__ int s[256];
    int t = threadIdx.x;
    int v = (t < NBLK) ? bsum[t] : 0;
    s[t] = v;
    __syncthreads();
    for (int off = 1; off < 256; off <<= 1) {
        int u = (t >= off) ? s[t - off] : 0;
        __syncthreads();
        s[t] += u;
        __syncthreads();
    }
    if (t < NBLK) boff[t] = s[t] - v;   // exclusive of block sums
}

__global__ void blk_scan(const int* __restrict__ cnt, const int* __restrict__ boff,
                         int* __restrict__ base) {
    __shared__ int s[256];
    int t = threadIdx.x;
    int idx = blockIdx.x * 256 + t;
    int v = (idx < NNODES) ? cnt[idx] : 0;
    s[t] = v;
    __syncthreads();
    for (int off = 1; off < 256; off <<= 1) {
        int u = (t >= off) ? s[t - off] : 0;
        __syncthreads();
        s[t] += u;
        __syncthreads();
    }
    if (idx < NNODES) base[idx] = boff[blockIdx.x] + s[t] - v;  // exclusive
    if (idx == 0) base[NNODES] = NDIR;
}

// ---- CSR fill: col[base[r] + fill[r]++] = c ------------------------------
__global__ void fill_csr(const int* __restrict__ au, const int* __restrict__ ai,
                         const int* __restrict__ base, int* __restrict__ fillc,
                         int* __restrict__ col) {
    int e = blockIdx.x * blockDim.x + threadIdx.x;
    if (e >= NDIR) return;
    int r, c;
    if (e < N_EDGES) { r = au[e];                  c = N_USERS + ai[e]; }
    else             { int k = e - N_EDGES; r = N_USERS + ai[k]; c = au[k]; }
    int pos = base[r] + atomicAdd(&fillc[r], 1);
    col[pos] = c;
}

// ---- z(bf16) = zacc(f32) = dinv[row] * concat(user_emb, item_emb) --------
// one thread per 4 elems: writes uint2 (4 bf16) + float4
__global__ void init_z(const float4* __restrict__ ue, const float4* __restrict__ ie,
                       const float* __restrict__ dinv,
                       uint2* __restrict__ z, float4* __restrict__ zacc) {
    const int NU4 = N_USERS * D / 4;
    const int NT4 = NNODES * D / 4;
    int i = blockIdx.x * blockDim.x + threadIdx.x;
    if (i >= NT4) return;
    float4 v = (i < NU4) ? ue[i] : ie[i - NU4];
    float w = dinv[i >> 5];          // D/4 = 32 float4 per row
    v.x *= w; v.y *= w; v.z *= w; v.w *= w;
    zacc[i] = v;
    uint2 p;
    p.x = bf16x2_pack(v.x, v.y);
    p.y = bf16x2_pack(v.z, v.w);
    z[i] = p;
}

// ---- SpMM gather in z-space (bf16 z, fp32 accumulate), one wave per row --
// znxt[r] = dinv2[r] * sum_{c in N(r)} z[c];  zacc[r] += znxt[r]
// Row = 128 bf16 = 256B; lane holds one uint (2 elems).
template <bool WRITE_NXT>
__global__ void spmm_gather(const int* __restrict__ base, const int* __restrict__ col,
                            const float* __restrict__ dinv2,
                            const unsigned* __restrict__ z,   // bf16x2, 64 uints/row
                            unsigned* __restrict__ znxt,      // bf16x2
                            float* __restrict__ zacc) {
    int row  = (blockIdx.x * blockDim.x + threadIdx.x) >> 6;
    int lane = threadIdx.x & 63;
    if (row >= NNODES) return;
    int s = base[row], e = base[row + 1];
    float2 s0 = make_float2(0.f, 0.f);
    float2 s1 = make_float2(0.f, 0.f);
    int j = s;
    for (; j + 3 < e; j += 4) {
        int c0 = col[j], c1 = col[j + 1], c2 = col[j + 2], c3 = col[j + 3];
        unsigned t0 = z[(size_t)c0 * 64 + lane];
        unsigned t1 = z[(size_t)c1 * 64 + lane];
        unsigned t2 = z[(size_t)c2 * 64 + lane];
        unsigned t3 = z[(size_t)c3 * 64 + lane];
        s0.x += bf16_lo(t0); s0.y += bf16_hi(t0);
        s1.x += bf16_lo(t1); s1.y += bf16_hi(t1);
        s0.x += bf16_lo(t2); s0.y += bf16_hi(t2);
        s1.x += bf16_lo(t3); s1.y += bf16_hi(t3);
    }
    for (; j < e; ++j) {
        unsigned t0 = z[(size_t)col[j] * 64 + lane];
        s0.x += bf16_lo(t0); s0.y += bf16_hi(t0);
    }
    float w = dinv2[row];
    float2 y = make_float2(w * (s0.x + s1.x), w * (s0.y + s1.y));
    if (WRITE_NXT)
        znxt[(size_t)row * 64 + lane] = bf16x2_pack(y.x, y.y);
    float2* ar = (float2*)(zacc + (size_t)row * D);
    float2 a = ar[lane];
    a.x += y.x; a.y += y.y;
    ar[lane] = a;
}

// ---- BPR loss on z-space acc: unscale after the dot reduction ------------
// x_acc = zacc/dinv; all_emb = x_acc/4 => diff = (sp/(du*dp) - sn/(du*dn))/16
__global__ void bpr_loss(const float* __restrict__ zacc, const float* __restrict__ dinv,
                         const int* __restrict__ user, const int* __restrict__ pos,
                         const int* __restrict__ neg, float* __restrict__ lacc) {
    __shared__ float s[4];
    int gw   = (blockIdx.x * blockDim.x + threadIdx.x) >> 6;
    int lane = threadIdx.x & 63;
    int wv   = threadIdx.x >> 6;
    float ls = 0.0f;
    if (gw < BATCH) {
        int u = user[gw];
        int p = N_USERS + pos[gw] - 1;   // 1-indexed items
        int n = N_USERS + neg[gw] - 1;
        const float2* tu = (const float2*)(zacc + (size_t)u * D);
        const float2* pi = (const float2*)(zacc + (size_t)p * D);
        const float2* ni = (const float2*)(zacc + (size_t)n * D);
        float2 a = tu[lane], b = pi[lane], c = ni[lane];
        float sp = a.x * b.x + a.y * b.y;
        float sn = a.x * c.x + a.y * c.y;
        #pragma unroll
        for (int off = 32; off; off >>= 1) {
            sp += __shfl_down(sp, off);
            sn += __shfl_down(sn, off);
        }
        if (lane == 0) {
            float du = dinv[u], dp = dinv[p], dn = dinv[n];
            float diff = (sp / (du * dp) - sn / (du * dn)) * (1.0f / 16.0f);
            // log_sigmoid(x) = min(x,0) - log1p(exp(-|x|))
            ls = fminf(diff, 0.0f) - log1pf(expf(-fabsf(diff)));
        }
    }
    if (lane == 0) s[wv] = ls;
    __syncthreads();
    if (threadIdx.x == 0) atomicAdd(lacc, s[0] + s[1] + s[2] + s[3]);
}

__global__ void finalize(const float* __restrict__ lacc, float* __restrict__ out) {
    out[0] = -lacc[0] * (1.0f / (float)BATCH);
}

extern "C" void kernel_launch(void* const* d_in, const int* in_sizes, int n_in,
                              void* d_out, int out_size, void* d_ws, size_t ws_size,
                              hipStream_t stream) {
    const float* ue  = (const float*)d_in[0];
    const float* ie  = (const float*)d_in[1];
    const int*   au  = (const int*)d_in[2];
    const int*   ai  = (const int*)d_in[3];
    const int*   usr = (const int*)d_in[4];
    const int*   pos = (const int*)d_in[5];
    const int*   neg = (const int*)d_in[6];
    float*       out = (float*)d_out;

    const size_t XN  = (size_t)NNODES * D;      // 7,680,000 elems
    const size_t XNH = XN / 2;                  // uints for bf16 z

    // ws layout (16B-aligned chunks):
    // zacc(f32) | za(bf16) | zb(bf16) | dinv | dinv2 |
    // [cnt | fillc | lacc]  <- one contiguous memset region | base[60008] | col | bsum | boff
    float*    zacc  = (float*)d_ws;
    unsigned* za    = (unsigned*)(zacc + XN);
    unsigned* zb    = za + XNH;
    float*    dinv  = (float*)(zb + XNH);
    float*    dinv2 = dinv + NNODES;
    int*      cnt   = (int*)(dinv2 + NNODES);
    int*      fillc = cnt + NNODES;
    float*    lacc  = (float*)(fillc + NNODES);
    int*      base  = (int*)(lacc + 4);         // keep 16B align
    int*      col   = base + 60008;             // NNODES+1 rounded up
    int*      bsum  = col + NDIR;
    int*      boff  = bsum + 256;

    const int NT4 = NNODES * D / 4;

    // cnt + fillc + lacc zeroed in one shot
    hipMemsetAsync(cnt, 0, (2 * NNODES + 4) * sizeof(int), stream);

    deg_count<<<(N_EDGES + 255) / 256, 256, 0, stream>>>(au, ai, cnt);
    blk_reduce<<<NBLK, 256, 0, stream>>>(cnt, bsum, dinv, dinv2);
    scan_tops<<<1, 256, 0, stream>>>(bsum, boff);
    blk_scan<<<NBLK, 256, 0, stream>>>(cnt, boff, base);
    fill_csr<<<(NDIR + 255) / 256, 256, 0, stream>>>(au, ai, base, fillc, col);
    init_z<<<(NT4 + 255) / 256, 256, 0, stream>>>((const float4*)ue, (const float4*)ie,
                                                  dinv, (uint2*)za, (float4*)zacc);

    const int SPMM_BLOCKS = (NNODES + 3) / 4;   // 4 waves (rows) per block
    spmm_gather<true ><<<SPMM_BLOCKS, 256, 0, stream>>>(base, col, dinv2, za, zb, zacc);
    spmm_gather<true ><<<SPMM_BLOCKS, 256, 0, stream>>>(base, col, dinv2, zb, za, zacc);
    spmm_gather<false><<<SPMM_BLOCKS, 256, 0, stream>>>(base, col, dinv2, za, zb, zacc);

    bpr_loss<<<BATCH / 4, 256, 0, stream>>>(zacc, dinv, usr, pos, neg, lacc);
    finalize<<<1, 1, 0, stream>>>(lacc, out);
}

// Round 5
// 254.122 us; speedup vs baseline: 6.8793x; 1.1304x over previous
//
#include <hip/hip_runtime.h>
#include <math.h>

#define N_USERS 40000
#define N_ITEMS 20000
#define NNODES  60000          // N_USERS + N_ITEMS
#define D       128
#define N_EDGES 320000
#define NDIR    (2 * N_EDGES)  // directed edges
#define LAYERS  3
#define EPS_    1e-7f
#define BATCH   4096
#define NBLK    ((NNODES + 255) / 256)   // 235 scan blocks

__device__ __forceinline__ unsigned bf16x2_pack(float a, float b) {
    // round-to-nearest-even f32 -> bf16, packed low/high
    unsigned ua = __float_as_uint(a);
    unsigned ub = __float_as_uint(b);
    ua = (ua + 0x7FFF + ((ua >> 16) & 1)) >> 16;
    ub = (ub + 0x7FFF + ((ub >> 16) & 1)) >> 16;
    return ua | (ub << 16);
}
__device__ __forceinline__ float bf16_lo(unsigned p) { return __uint_as_float(p << 16); }
__device__ __forceinline__ float bf16_hi(unsigned p) { return __uint_as_float(p & 0xFFFF0000u); }

// ---- degree count (int): cnt[r] += 1 per directed edge -------------------
__global__ void deg_count(const int* __restrict__ au, const int* __restrict__ ai,
                          int* __restrict__ cnt) {
    int e = blockIdx.x * blockDim.x + threadIdx.x;
    if (e >= N_EDGES) return;
    atomicAdd(&cnt[au[e]], 1);
    atomicAdd(&cnt[N_USERS + ai[e]], 1);
}

// ---- fused: per-block sum of cnt + dinv/dinv2 ----------------------------
__global__ void blk_reduce(const int* __restrict__ cnt, int* __restrict__ bsum,
                           float* __restrict__ dinv, float* __restrict__ dinv2) {
    int idx = blockIdx.x * 256 + threadIdx.x;
    int v = 0;
    if (idx < NNODES) {
        v = cnt[idx];
        float w = rsqrtf((float)v + EPS_);
        dinv[idx] = w;
        dinv2[idx] = w * w;
    }
    int r = v;
    #pragma unroll
    for (int off = 32; off; off >>= 1) r += __shfl_down(r, off);
    __shared__ int s[4];
    if ((threadIdx.x & 63) == 0) s[threadIdx.x >> 6] = r;
    __syncthreads();
    if (threadIdx.x == 0) bsum[blockIdx.x] = s[0] + s[1] + s[2] + s[3];
}

__global__ void scan_tops(const int* __restrict__ bsum, int* __restrict__ boff) {
    __shared__ int s[256];
    int t = threadIdx.x;
    int v = (t < NBLK) ? bsum[t] : 0;
    s[t] = v;
    __syncthreads();
    for (int off = 1; off < 256; off <<= 1) {
        int u = (t >= off) ? s[t - off] : 0;
        __syncthreads();
        s[t] += u;
        __syncthreads();
    }
    if (t < NBLK) boff[t] = s[t] - v;   // exclusive of block sums
}

__global__ void blk_scan(const int* __restrict__ cnt, const int* __restrict__ boff,
                         int* __restrict__ base) {
    __shared__ int s[256];
    int t = threadIdx.x;
    int idx = blockIdx.x * 256 + t;
    int v = (idx < NNODES) ? cnt[idx] : 0;
    s[t] = v;
    __syncthreads();
    for (int off = 1; off < 256; off <<= 1) {
        int u = (t >= off) ? s[t - off] : 0;
        __syncthreads();
        s[t] += u;
        __syncthreads();
    }
    if (idx < NNODES) base[idx] = boff[blockIdx.x] + s[t] - v;  // exclusive
    if (idx == 0) base[NNODES] = NDIR;
}

// ---- CSR fill: col[base[r] + fill[r]++] = c ------------------------------
__global__ void fill_csr(const int* __restrict__ au, const int* __restrict__ ai,
                         const int* __restrict__ base, int* __restrict__ fillc,
                         int* __restrict__ col) {
    int e = blockIdx.x * blockDim.x + threadIdx.x;
    if (e >= NDIR) return;
    int r, c;
    if (e < N_EDGES) { r = au[e];                  c = N_USERS + ai[e]; }
    else             { int k = e - N_EDGES; r = N_USERS + ai[k]; c = au[k]; }
    int pos = base[r] + atomicAdd(&fillc[r], 1);
    col[pos] = c;
}

// ---- z0(bf16) = dinv[row] * concat(user_emb, item_emb) -------------------
__global__ void init_z(const float4* __restrict__ ue, const float4* __restrict__ ie,
                       const float* __restrict__ dinv, uint2* __restrict__ z0) {
    const int NU4 = N_USERS * D / 4;
    const int NT4 = NNODES * D / 4;
    int i = blockIdx.x * blockDim.x + threadIdx.x;
    if (i >= NT4) return;
    float4 v = (i < NU4) ? ue[i] : ie[i - NU4];
    float w = dinv[i >> 5];          // D/4 = 32 float4 per row
    uint2 p;
    p.x = bf16x2_pack(v.x * w, v.y * w);
    p.y = bf16x2_pack(v.z * w, v.w * w);
    z0[i] = p;
}

// ---- shared gather body: znxt[row] = dinv2[row] * sum_{c in N(row)} z[c] --
__device__ __forceinline__ void gather_row(int row, int lane,
                                           const int* __restrict__ base,
                                           const int* __restrict__ col,
                                           const float* __restrict__ dinv2,
                                           const unsigned* __restrict__ z,
                                           unsigned* __restrict__ znxt) {
    int s = base[row], e = base[row + 1];
    float2 s0 = make_float2(0.f, 0.f);
    float2 s1 = make_float2(0.f, 0.f);
    int j = s;
    for (; j + 3 < e; j += 4) {
        int c0 = col[j], c1 = col[j + 1], c2 = col[j + 2], c3 = col[j + 3];
        unsigned t0 = z[(size_t)c0 * 64 + lane];
        unsigned t1 = z[(size_t)c1 * 64 + lane];
        unsigned t2 = z[(size_t)c2 * 64 + lane];
        unsigned t3 = z[(size_t)c3 * 64 + lane];
        s0.x += bf16_lo(t0); s0.y += bf16_hi(t0);
        s1.x += bf16_lo(t1); s1.y += bf16_hi(t1);
        s0.x += bf16_lo(t2); s0.y += bf16_hi(t2);
        s1.x += bf16_lo(t3); s1.y += bf16_hi(t3);
    }
    for (; j < e; ++j) {
        unsigned t0 = z[(size_t)col[j] * 64 + lane];
        s0.x += bf16_lo(t0); s0.y += bf16_hi(t0);
    }
    float w = dinv2[row];
    znxt[(size_t)row * 64 + lane] =
        bf16x2_pack(w * (s0.x + s1.x), w * (s0.y + s1.y));
}

// ---- full SpMM: one wave per row, all NNODES rows ------------------------
__global__ void spmm_full(const int* __restrict__ base, const int* __restrict__ col,
                          const float* __restrict__ dinv2,
                          const unsigned* __restrict__ z, unsigned* __restrict__ znxt) {
    int row  = (blockIdx.x * blockDim.x + threadIdx.x) >> 6;
    int lane = threadIdx.x & 63;
    if (row >= NNODES) return;
    gather_row(row, lane, base, col, dinv2, z, znxt);
}

// ---- batch-restricted SpMM: rows = {user} ∪ {pos-1} ∪ {neg-1} ------------
// Duplicate rows write identical values (benign race).
__global__ void spmm_batch(const int* __restrict__ base, const int* __restrict__ col,
                           const float* __restrict__ dinv2,
                           const unsigned* __restrict__ z, unsigned* __restrict__ znxt,
                           const int* __restrict__ user, const int* __restrict__ pos,
                           const int* __restrict__ neg) {
    int w    = (blockIdx.x * blockDim.x + threadIdx.x) >> 6;
    int lane = threadIdx.x & 63;
    if (w >= 3 * BATCH) return;
    int row;
    if      (w < BATCH)     row = user[w];
    else if (w < 2 * BATCH) row = N_USERS + pos[w - BATCH] - 1;
    else                    row = N_USERS + neg[w - 2 * BATCH] - 1;
    gather_row(row, lane, base, col, dinv2, z, znxt);
}

// ---- BPR loss: sum z0..z3 at the 3 nodes, unscale, log-sigmoid -----------
// x_acc[node] = (z0+z1+z2+z3)[node] / dinv[node]; all_emb = x_acc/4
__device__ __forceinline__ float2 row_sum4(const unsigned* __restrict__ z0,
                                           const unsigned* __restrict__ z1,
                                           const unsigned* __restrict__ z2,
                                           const unsigned* __restrict__ z3,
                                           int node, int lane) {
    size_t o = (size_t)node * 64 + lane;
    unsigned a = z0[o], b = z1[o], c = z2[o], d = z3[o];
    return make_float2(bf16_lo(a) + bf16_lo(b) + bf16_lo(c) + bf16_lo(d),
                       bf16_hi(a) + bf16_hi(b) + bf16_hi(c) + bf16_hi(d));
}

__global__ void bpr_loss(const unsigned* __restrict__ z0, const unsigned* __restrict__ z1,
                         const unsigned* __restrict__ z2, const unsigned* __restrict__ z3,
                         const float* __restrict__ dinv,
                         const int* __restrict__ user, const int* __restrict__ pos,
                         const int* __restrict__ neg, float* __restrict__ lacc) {
    __shared__ float s[4];
    int gw   = (blockIdx.x * blockDim.x + threadIdx.x) >> 6;
    int lane = threadIdx.x & 63;
    int wv   = threadIdx.x >> 6;
    float ls = 0.0f;
    if (gw < BATCH) {
        int u = user[gw];
        int p = N_USERS + pos[gw] - 1;   // 1-indexed items
        int n = N_USERS + neg[gw] - 1;
        float2 a = row_sum4(z0, z1, z2, z3, u, lane);
        float2 b = row_sum4(z0, z1, z2, z3, p, lane);
        float2 c = row_sum4(z0, z1, z2, z3, n, lane);
        float sp = a.x * b.x + a.y * b.y;
        float sn = a.x * c.x + a.y * c.y;
        #pragma unroll
        for (int off = 32; off; off >>= 1) {
            sp += __shfl_down(sp, off);
            sn += __shfl_down(sn, off);
        }
        if (lane == 0) {
            float du = dinv[u], dp = dinv[p], dn = dinv[n];
            float diff = (sp / (du * dp) - sn / (du * dn)) * (1.0f / 16.0f);
            // log_sigmoid(x) = min(x,0) - log1p(exp(-|x|))
            ls = fminf(diff, 0.0f) - log1pf(expf(-fabsf(diff)));
        }
    }
    if (lane == 0) s[wv] = ls;
    __syncthreads();
    if (threadIdx.x == 0) atomicAdd(lacc, s[0] + s[1] + s[2] + s[3]);
}

__global__ void finalize(const float* __restrict__ lacc, float* __restrict__ out) {
    out[0] = -lacc[0] * (1.0f / (float)BATCH);
}

extern "C" void kernel_launch(void* const* d_in, const int* in_sizes, int n_in,
                              void* d_out, int out_size, void* d_ws, size_t ws_size,
                              hipStream_t stream) {
    const float* ue  = (const float*)d_in[0];
    const float* ie  = (const float*)d_in[1];
    const int*   au  = (const int*)d_in[2];
    const int*   ai  = (const int*)d_in[3];
    const int*   usr = (const int*)d_in[4];
    const int*   pos = (const int*)d_in[5];
    const int*   neg = (const int*)d_in[6];
    float*       out = (float*)d_out;

    const size_t XNH = (size_t)NNODES * D / 2;  // uints per bf16 z buffer

    // ws layout (16B-aligned chunks):
    // z0 | z1 | z2 | z3 (bf16) | dinv | dinv2 |
    // [cnt | fillc | lacc] <- one contiguous memset | base[60008] | col | bsum | boff
    unsigned* z0    = (unsigned*)d_ws;
    unsigned* z1    = z0 + XNH;
    unsigned* z2    = z1 + XNH;
    unsigned* z3    = z2 + XNH;
    float*    dinv  = (float*)(z3 + XNH);
    float*    dinv2 = dinv + NNODES;
    int*      cnt   = (int*)(dinv2 + NNODES);
    int*      fillc = cnt + NNODES;
    float*    lacc  = (float*)(fillc + NNODES);
    int*      base  = (int*)(lacc + 4);         // keep 16B align
    int*      col   = base + 60008;             // NNODES+1 rounded up
    int*      bsum  = col + NDIR;
    int*      boff  = bsum + 256;

    const int NT4 = NNODES * D / 4;

    // cnt + fillc + lacc zeroed in one shot
    hipMemsetAsync(cnt, 0, (2 * NNODES + 4) * sizeof(int), stream);

    deg_count<<<(N_EDGES + 255) / 256, 256, 0, stream>>>(au, ai, cnt);
    blk_reduce<<<NBLK, 256, 0, stream>>>(cnt, bsum, dinv, dinv2);
    scan_tops<<<1, 256, 0, stream>>>(bsum, boff);
    blk_scan<<<NBLK, 256, 0, stream>>>(cnt, boff, base);
    fill_csr<<<(NDIR + 255) / 256, 256, 0, stream>>>(au, ai, base, fillc, col);
    init_z<<<(NT4 + 255) / 256, 256, 0, stream>>>((const float4*)ue, (const float4*)ie,
                                                  dinv, (uint2*)z0);

    const int FULL_BLOCKS = (NNODES + 3) / 4;    // 4 rows (waves) per block
    spmm_full<<<FULL_BLOCKS, 256, 0, stream>>>(base, col, dinv2, z0, z1);
    spmm_full<<<FULL_BLOCKS, 256, 0, stream>>>(base, col, dinv2, z1, z2);
    spmm_batch<<<(3 * BATCH) / 4, 256, 0, stream>>>(base, col, dinv2, z2, z3,
                                                    usr, pos, neg);

    bpr_loss<<<BATCH / 4, 256, 0, stream>>>(z0, z1, z2, z3, dinv, usr, pos, neg, lacc);
    finalize<<<1, 1, 0, stream>>>(lacc, out);
}

// Round 6
// 241.326 us; speedup vs baseline: 7.2440x; 1.0530x over previous
//
#include <hip/hip_runtime.h>
#include <math.h>

#define N_USERS 40000
#define N_ITEMS 20000
#define NNODES  60000          // N_USERS + N_ITEMS
#define D       128
#define N_EDGES 320000
#define NDIR    (2 * N_EDGES)  // directed edges
#define LAYERS  3
#define EPS_    1e-7f
#define BATCH   4096
#define NBLK    ((NNODES + 255) / 256)   // 235 scan blocks
#define BPR_BLOCKS (BATCH / 4)           // 1024, 4 waves per block

__device__ __forceinline__ unsigned bf16x2_pack(float a, float b) {
    // round-to-nearest-even f32 -> bf16, packed low/high
    unsigned ua = __float_as_uint(a);
    unsigned ub = __float_as_uint(b);
    ua = (ua + 0x7FFF + ((ua >> 16) & 1)) >> 16;
    ub = (ub + 0x7FFF + ((ub >> 16) & 1)) >> 16;
    return ua | (ub << 16);
}
__device__ __forceinline__ float bf16_lo(unsigned p) { return __uint_as_float(p << 16); }
__device__ __forceinline__ float bf16_hi(unsigned p) { return __uint_as_float(p & 0xFFFF0000u); }

// ---- degree count (int): cnt[r] += 1 per directed edge -------------------
__global__ void deg_count(const int* __restrict__ au, const int* __restrict__ ai,
                          int* __restrict__ cnt) {
    int e = blockIdx.x * blockDim.x + threadIdx.x;
    if (e >= N_EDGES) return;
    atomicAdd(&cnt[au[e]], 1);
    atomicAdd(&cnt[N_USERS + ai[e]], 1);
}

// ---- fused: per-block sum of cnt + dinv/dinv2 ----------------------------
__global__ void blk_reduce(const int* __restrict__ cnt, int* __restrict__ bsum,
                           float* __restrict__ dinv, float* __restrict__ dinv2) {
    int idx = blockIdx.x * 256 + threadIdx.x;
    int v = 0;
    if (idx < NNODES) {
        v = cnt[idx];
        float w = rsqrtf((float)v + EPS_);
        dinv[idx] = w;
        dinv2[idx] = w * w;
    }
    int r = v;
    #pragma unroll
    for (int off = 32; off; off >>= 1) r += __shfl_down(r, off);
    __shared__ int s[4];
    if ((threadIdx.x & 63) == 0) s[threadIdx.x >> 6] = r;
    __syncthreads();
    if (threadIdx.x == 0) bsum[blockIdx.x] = s[0] + s[1] + s[2] + s[3];
}

__global__ void scan_tops(const int* __restrict__ bsum, int* __restrict__ boff) {
    __shared__ int s[256];
    int t = threadIdx.x;
    int v = (t < NBLK) ? bsum[t] : 0;
    s[t] = v;
    __syncthreads();
    for (int off = 1; off < 256; off <<= 1) {
        int u = (t >= off) ? s[t - off] : 0;
        __syncthreads();
        s[t] += u;
        __syncthreads();
    }
    if (t < NBLK) boff[t] = s[t] - v;   // exclusive of block sums
}

__global__ void blk_scan(const int* __restrict__ cnt, const int* __restrict__ boff,
                         int* __restrict__ base) {
    __shared__ int s[256];
    int t = threadIdx.x;
    int idx = blockIdx.x * 256 + t;
    int v = (idx < NNODES) ? cnt[idx] : 0;
    s[t] = v;
    __syncthreads();
    for (int off = 1; off < 256; off <<= 1) {
        int u = (t >= off) ? s[t - off] : 0;
        __syncthreads();
        s[t] += u;
        __syncthreads();
    }
    if (idx < NNODES) base[idx] = boff[blockIdx.x] + s[t] - v;  // exclusive
    if (idx == 0) base[NNODES] = NDIR;
}

// ---- CSR fill: col[base[r] + fill[r]++] = c ------------------------------
__global__ void fill_csr(const int* __restrict__ au, const int* __restrict__ ai,
                         const int* __restrict__ base, int* __restrict__ fillc,
                         int* __restrict__ col) {
    int e = blockIdx.x * blockDim.x + threadIdx.x;
    if (e >= NDIR) return;
    int r, c;
    if (e < N_EDGES) { r = au[e];                  c = N_USERS + ai[e]; }
    else             { int k = e - N_EDGES; r = N_USERS + ai[k]; c = au[k]; }
    int pos = base[r] + atomicAdd(&fillc[r], 1);
    col[pos] = c;
}

// ---- z0(bf16) = dinv[row] * concat(user_emb, item_emb) -------------------
__global__ void init_z(const float4* __restrict__ ue, const float4* __restrict__ ie,
                       const float* __restrict__ dinv, uint2* __restrict__ z0) {
    const int NU4 = N_USERS * D / 4;
    const int NT4 = NNODES * D / 4;
    int i = blockIdx.x * blockDim.x + threadIdx.x;
    if (i >= NT4) return;
    float4 v = (i < NU4) ? ue[i] : ie[i - NU4];
    float w = dinv[i >> 5];          // D/4 = 32 float4 per row
    uint2 p;
    p.x = bf16x2_pack(v.x * w, v.y * w);
    p.y = bf16x2_pack(v.z * w, v.w * w);
    z0[i] = p;
}

__device__ __forceinline__ void add_u4(float* acc, uint4 t) {
    acc[0] += bf16_lo(t.x); acc[1] += bf16_hi(t.x);
    acc[2] += bf16_lo(t.y); acc[3] += bf16_hi(t.y);
    acc[4] += bf16_lo(t.z); acc[5] += bf16_hi(t.z);
    acc[6] += bf16_lo(t.w); acc[7] += bf16_hi(t.w);
}

// ---- full SpMM, quarter-wave rows: 16 lanes x uint4 = 256B row -----------
// znxt[r] = bf16( dinv2[r] * sum_{c in N(r)} z[c] )
__global__ void spmm_full(const int* __restrict__ base, const int* __restrict__ col,
                          const float* __restrict__ dinv2,
                          const uint4* __restrict__ z, uint4* __restrict__ znxt) {
    int tid = blockIdx.x * 256 + threadIdx.x;
    int row = tid >> 4;               // 16 rows per 256-thread block
    int sub = threadIdx.x & 15;       // lane within quarter
    if (row >= NNODES) return;
    int s = base[row], e = base[row + 1];
    float a0[8] = {0,0,0,0,0,0,0,0};
    float a1[8] = {0,0,0,0,0,0,0,0};
    int j = s;
    for (; j + 3 < e; j += 4) {
        int c0 = col[j], c1 = col[j + 1], c2 = col[j + 2], c3 = col[j + 3];
        uint4 t0 = z[(c0 << 4) + sub];   // row stride = 16 uint4
        uint4 t1 = z[(c1 << 4) + sub];
        uint4 t2 = z[(c2 << 4) + sub];
        uint4 t3 = z[(c3 << 4) + sub];
        add_u4(a0, t0); add_u4(a1, t1);
        add_u4(a0, t2); add_u4(a1, t3);
    }
    for (; j < e; ++j) {
        uint4 t0 = z[(col[j] << 4) + sub];
        add_u4(a0, t0);
    }
    float w = dinv2[row];
    uint4 o;
    o.x = bf16x2_pack(w * (a0[0] + a1[0]), w * (a0[1] + a1[1]));
    o.y = bf16x2_pack(w * (a0[2] + a1[2]), w * (a0[3] + a1[3]));
    o.z = bf16x2_pack(w * (a0[4] + a1[4]), w * (a0[5] + a1[5]));
    o.w = bf16x2_pack(w * (a0[6] + a1[6]), w * (a0[7] + a1[7]));
    znxt[(row << 4) + sub] = o;
}

// ---- f32 gather of one row (64-lane layout, lane holds 2 elems) ----------
__device__ __forceinline__ float2 gather_row_f32(int row, int lane,
                                                 const int* __restrict__ base,
                                                 const int* __restrict__ col,
                                                 const float* __restrict__ dinv2,
                                                 const unsigned* __restrict__ z) {
    int s = base[row], e = base[row + 1];
    float2 s0 = make_float2(0.f, 0.f);
    float2 s1 = make_float2(0.f, 0.f);
    int j = s;
    for (; j + 3 < e; j += 4) {
        int c0 = col[j], c1 = col[j + 1], c2 = col[j + 2], c3 = col[j + 3];
        unsigned t0 = z[(size_t)c0 * 64 + lane];
        unsigned t1 = z[(size_t)c1 * 64 + lane];
        unsigned t2 = z[(size_t)c2 * 64 + lane];
        unsigned t3 = z[(size_t)c3 * 64 + lane];
        s0.x += bf16_lo(t0); s0.y += bf16_hi(t0);
        s1.x += bf16_lo(t1); s1.y += bf16_hi(t1);
        s0.x += bf16_lo(t2); s0.y += bf16_hi(t2);
        s1.x += bf16_lo(t3); s1.y += bf16_hi(t3);
    }
    for (; j < e; ++j) {
        unsigned t0 = z[(size_t)col[j] * 64 + lane];
        s0.x += bf16_lo(t0); s0.y += bf16_hi(t0);
    }
    float w = dinv2[row];
    return make_float2(w * (s0.x + s1.x), w * (s0.y + s1.y));
}

// ---- z0+z1+z2 at node (lane holds 2 elems) -------------------------------
__device__ __forceinline__ float2 row_sum3(const unsigned* __restrict__ z0,
                                           const unsigned* __restrict__ z1,
                                           const unsigned* __restrict__ z2,
                                           int node, int lane) {
    size_t o = (size_t)node * 64 + lane;
    unsigned a = z0[o], b = z1[o], c = z2[o];
    return make_float2(bf16_lo(a) + bf16_lo(b) + bf16_lo(c),
                       bf16_hi(a) + bf16_hi(b) + bf16_hi(c));
}

// ---- fused BPR loss: layer-3 gather inline (f32), last block finalizes ---
// zsum[node] = z0+z1+z2+z3; x_acc = zsum/dinv; all_emb = x_acc/4
// diff = (sp/(du*dp) - sn/(du*dn))/16; loss = -mean(log_sigmoid(diff))
__global__ void bpr_loss(const unsigned* __restrict__ z0, const unsigned* __restrict__ z1,
                         const unsigned* __restrict__ z2,
                         const float* __restrict__ dinv, const float* __restrict__ dinv2,
                         const int* __restrict__ base, const int* __restrict__ col,
                         const int* __restrict__ user, const int* __restrict__ pos,
                         const int* __restrict__ neg,
                         float* __restrict__ lacc, int* __restrict__ done,
                         float* __restrict__ out) {
    __shared__ float s[4];
    int gw   = (blockIdx.x * blockDim.x + threadIdx.x) >> 6;
    int lane = threadIdx.x & 63;
    int wv   = threadIdx.x >> 6;
    float ls = 0.0f;
    if (gw < BATCH) {
        int u = user[gw];
        int p = N_USERS + pos[gw] - 1;   // 1-indexed items
        int n = N_USERS + neg[gw] - 1;
        float2 gu = gather_row_f32(u, lane, base, col, dinv2, z2);
        float2 gp = gather_row_f32(p, lane, base, col, dinv2, z2);
        float2 gn = gather_row_f32(n, lane, base, col, dinv2, z2);
        float2 a = row_sum3(z0, z1, z2, u, lane);
        float2 b = row_sum3(z0, z1, z2, p, lane);
        float2 c = row_sum3(z0, z1, z2, n, lane);
        a.x += gu.x; a.y += gu.y;
        b.x += gp.x; b.y += gp.y;
        c.x += gn.x; c.y += gn.y;
        float sp = a.x * b.x + a.y * b.y;
        float sn = a.x * c.x + a.y * c.y;
        #pragma unroll
        for (int off = 32; off; off >>= 1) {
            sp += __shfl_down(sp, off);
            sn += __shfl_down(sn, off);
        }
        if (lane == 0) {
            float du = dinv[u], dp = dinv[p], dn = dinv[n];
            float diff = (sp / (du * dp) - sn / (du * dn)) * (1.0f / 16.0f);
            // log_sigmoid(x) = min(x,0) - log1p(exp(-|x|))
            ls = fminf(diff, 0.0f) - log1pf(expf(-fabsf(diff)));
        }
    }
    if (lane == 0) s[wv] = ls;
    __syncthreads();
    if (threadIdx.x == 0) {
        atomicAdd(lacc, s[0] + s[1] + s[2] + s[3]);
        __threadfence();
        int prev = atomicAdd(done, 1);
        if (prev == BPR_BLOCKS - 1) {
            float total = atomicAdd(lacc, 0.0f);   // coherent read at LLC
            out[0] = -total * (1.0f / (float)BATCH);
        }
    }
}

extern "C" void kernel_launch(void* const* d_in, const int* in_sizes, int n_in,
                              void* d_out, int out_size, void* d_ws, size_t ws_size,
                              hipStream_t stream) {
    const float* ue  = (const float*)d_in[0];
    const float* ie  = (const float*)d_in[1];
    const int*   au  = (const int*)d_in[2];
    const int*   ai  = (const int*)d_in[3];
    const int*   usr = (const int*)d_in[4];
    const int*   pos = (const int*)d_in[5];
    const int*   neg = (const int*)d_in[6];
    float*       out = (float*)d_out;

    const size_t XNH = (size_t)NNODES * D / 2;  // uints per bf16 z buffer

    // ws layout (16B-aligned chunks):
    // z0 | z1 | z2 (bf16) | dinv | dinv2 |
    // [cnt | fillc | lacc | done] <- one contiguous memset | base[60008] | col | bsum | boff
    unsigned* z0    = (unsigned*)d_ws;
    unsigned* z1    = z0 + XNH;
    unsigned* z2    = z1 + XNH;
    float*    dinv  = (float*)(z2 + XNH);
    float*    dinv2 = dinv + NNODES;
    int*      cnt   = (int*)(dinv2 + NNODES);
    int*      fillc = cnt + NNODES;
    float*    lacc  = (float*)(fillc + NNODES);
    int*      done  = (int*)(lacc + 1);
    int*      base  = (int*)(lacc + 4);         // keep 16B align
    int*      col   = base + 60008;             // NNODES+1 rounded up
    int*      bsum  = col + NDIR;
    int*      boff  = bsum + 256;

    const int NT4 = NNODES * D / 4;

    // cnt + fillc + lacc + done zeroed in one shot
    hipMemsetAsync(cnt, 0, (2 * NNODES + 4) * sizeof(int), stream);

    deg_count<<<(N_EDGES + 255) / 256, 256, 0, stream>>>(au, ai, cnt);
    blk_reduce<<<NBLK, 256, 0, stream>>>(cnt, bsum, dinv, dinv2);
    scan_tops<<<1, 256, 0, stream>>>(bsum, boff);
    blk_scan<<<NBLK, 256, 0, stream>>>(cnt, boff, base);
    fill_csr<<<(NDIR + 255) / 256, 256, 0, stream>>>(au, ai, base, fillc, col);
    init_z<<<(NT4 + 255) / 256, 256, 0, stream>>>((const float4*)ue, (const float4*)ie,
                                                  dinv, (uint2*)z0);

    const int FULL_BLOCKS = (NNODES + 15) / 16;   // 16 rows per block
    spmm_full<<<FULL_BLOCKS, 256, 0, stream>>>(base, col, dinv2,
                                               (const uint4*)z0, (uint4*)z1);
    spmm_full<<<FULL_BLOCKS, 256, 0, stream>>>(base, col, dinv2,
                                               (const uint4*)z1, (uint4*)z2);

    bpr_loss<<<BPR_BLOCKS, 256, 0, stream>>>(z0, z1, z2, dinv, dinv2, base, col,
                                             usr, pos, neg, lacc, done, out);
}

// Round 7
// 235.018 us; speedup vs baseline: 7.4385x; 1.0268x over previous
//
#include <hip/hip_runtime.h>
#include <math.h>

#define N_USERS 40000
#define N_ITEMS 20000
#define NNODES  60000          // N_USERS + N_ITEMS
#define D       128
#define N_EDGES 320000
#define NDIR    (2 * N_EDGES)  // directed edges
#define LAYERS  3
#define EPS_    1e-7f
#define BATCH   4096
#define NBLK    ((NNODES + 255) / 256)   // 235 scan blocks
#define BPR_BLOCKS (BATCH / 4)           // 1024 blocks, 1 wave per element
#define FILL_BLOCKS (NDIR / 256)         // 2500
#define INIT_BLOCKS (NNODES * D / 4 / 256) // 7500

__device__ __forceinline__ unsigned bf16x2_pack(float a, float b) {
    // round-to-nearest-even f32 -> bf16, packed low/high
    unsigned ua = __float_as_uint(a);
    unsigned ub = __float_as_uint(b);
    ua = (ua + 0x7FFF + ((ua >> 16) & 1)) >> 16;
    ub = (ub + 0x7FFF + ((ub >> 16) & 1)) >> 16;
    return ua | (ub << 16);
}
__device__ __forceinline__ float bf16_lo(unsigned p) { return __uint_as_float(p << 16); }
__device__ __forceinline__ float bf16_hi(unsigned p) { return __uint_as_float(p & 0xFFFF0000u); }

// ---- degree count (int): cnt[r] += 1 per directed edge -------------------
__global__ void deg_count(const int* __restrict__ au, const int* __restrict__ ai,
                          int* __restrict__ cnt) {
    int e = blockIdx.x * blockDim.x + threadIdx.x;
    if (e >= N_EDGES) return;
    atomicAdd(&cnt[au[e]], 1);
    atomicAdd(&cnt[N_USERS + ai[e]], 1);
}

// ---- fused: per-block sum of cnt + dinv/dinv2 ----------------------------
__global__ void blk_reduce(const int* __restrict__ cnt, int* __restrict__ bsum,
                           float* __restrict__ dinv, float* __restrict__ dinv2) {
    int idx = blockIdx.x * 256 + threadIdx.x;
    int v = 0;
    if (idx < NNODES) {
        v = cnt[idx];
        float w = rsqrtf((float)v + EPS_);
        dinv[idx] = w;
        dinv2[idx] = w * w;
    }
    int r = v;
    #pragma unroll
    for (int off = 32; off; off >>= 1) r += __shfl_down(r, off);
    __shared__ int s[4];
    if ((threadIdx.x & 63) == 0) s[threadIdx.x >> 6] = r;
    __syncthreads();
    if (threadIdx.x == 0) bsum[blockIdx.x] = s[0] + s[1] + s[2] + s[3];
}

__global__ void scan_tops(const int* __restrict__ bsum, int* __restrict__ boff) {
    __shared__ int s[256];
    int t = threadIdx.x;
    int v = (t < NBLK) ? bsum[t] : 0;
    s[t] = v;
    __syncthreads();
    for (int off = 1; off < 256; off <<= 1) {
        int u = (t >= off) ? s[t - off] : 0;
        __syncthreads();
        s[t] += u;
        __syncthreads();
    }
    if (t < NBLK) boff[t] = s[t] - v;   // exclusive of block sums
}

__global__ void blk_scan(const int* __restrict__ cnt, const int* __restrict__ boff,
                         int* __restrict__ base) {
    __shared__ int s[256];
    int t = threadIdx.x;
    int idx = blockIdx.x * 256 + t;
    int v = (idx < NNODES) ? cnt[idx] : 0;
    s[t] = v;
    __syncthreads();
    for (int off = 1; off < 256; off <<= 1) {
        int u = (t >= off) ? s[t - off] : 0;
        __syncthreads();
        s[t] += u;
        __syncthreads();
    }
    if (idx < NNODES) base[idx] = boff[blockIdx.x] + s[t] - v;  // exclusive
    if (idx == 0) base[NNODES] = NDIR;
}

// ---- fused CSR fill + z0 init (disjoint block ranges) --------------------
__global__ void fill_and_init(const int* __restrict__ au, const int* __restrict__ ai,
                              const int* __restrict__ base, int* __restrict__ fillc,
                              int* __restrict__ col,
                              const float4* __restrict__ ue, const float4* __restrict__ ie,
                              const float* __restrict__ dinv, uint2* __restrict__ z0) {
    if (blockIdx.x < FILL_BLOCKS) {
        int e = blockIdx.x * 256 + threadIdx.x;
        int r, c;
        if (e < N_EDGES) { r = au[e];                  c = N_USERS + ai[e]; }
        else             { int k = e - N_EDGES; r = N_USERS + ai[k]; c = au[k]; }
        int pos = base[r] + atomicAdd(&fillc[r], 1);
        col[pos] = c;
    } else {
        const int NU4 = N_USERS * D / 4;
        int i = (blockIdx.x - FILL_BLOCKS) * 256 + threadIdx.x;
        float4 v = (i < NU4) ? ue[i] : ie[i - NU4];
        float w = dinv[i >> 5];          // D/4 = 32 float4 per row
        uint2 p;
        p.x = bf16x2_pack(v.x * w, v.y * w);
        p.y = bf16x2_pack(v.z * w, v.w * w);
        z0[i] = p;
    }
}

__device__ __forceinline__ void add_u4(float* acc, uint4 t) {
    acc[0] += bf16_lo(t.x); acc[1] += bf16_hi(t.x);
    acc[2] += bf16_lo(t.y); acc[3] += bf16_hi(t.y);
    acc[4] += bf16_lo(t.z); acc[5] += bf16_hi(t.z);
    acc[6] += bf16_lo(t.w); acc[7] += bf16_hi(t.w);
}

// ---- full SpMM, quarter-wave rows: 16 lanes x uint4 = 256B row -----------
// znxt[r] = bf16( dinv2[r] * sum_{c in N(r)} z[c] )
__global__ void spmm_full(const int* __restrict__ base, const int* __restrict__ col,
                          const float* __restrict__ dinv2,
                          const uint4* __restrict__ z, uint4* __restrict__ znxt) {
    int tid = blockIdx.x * 256 + threadIdx.x;
    int row = tid >> 4;               // 16 rows per 256-thread block
    int sub = threadIdx.x & 15;       // lane within quarter
    if (row >= NNODES) return;
    int s = base[row], e = base[row + 1];
    float a0[8] = {0,0,0,0,0,0,0,0};
    float a1[8] = {0,0,0,0,0,0,0,0};
    int j = s;
    for (; j + 3 < e; j += 4) {
        int c0 = col[j], c1 = col[j + 1], c2 = col[j + 2], c3 = col[j + 3];
        uint4 t0 = z[(c0 << 4) + sub];   // row stride = 16 uint4
        uint4 t1 = z[(c1 << 4) + sub];
        uint4 t2 = z[(c2 << 4) + sub];
        uint4 t3 = z[(c3 << 4) + sub];
        add_u4(a0, t0); add_u4(a1, t1);
        add_u4(a0, t2); add_u4(a1, t3);
    }
    for (; j < e; ++j) {
        uint4 t0 = z[(col[j] << 4) + sub];
        add_u4(a0, t0);
    }
    float w = dinv2[row];
    uint4 o;
    o.x = bf16x2_pack(w * (a0[0] + a1[0]), w * (a0[1] + a1[1]));
    o.y = bf16x2_pack(w * (a0[2] + a1[2]), w * (a0[3] + a1[3]));
    o.z = bf16x2_pack(w * (a0[4] + a1[4]), w * (a0[5] + a1[5]));
    o.w = bf16x2_pack(w * (a0[6] + a1[6]), w * (a0[7] + a1[7]));
    znxt[(row << 4) + sub] = o;
}

// ---- fused BPR loss, quarter-wave: one wave per element, u/p/n in q0/q1/q2
// zsum[node] = z0+z1+z2 + inline layer-3 gather from z2 (f32).
// x_acc = zsum/dinv; all_emb = x_acc/4 => diff = (sp/(du*dp) - sn/(du*dn))/16
__global__ void bpr_loss(const uint4* __restrict__ z0, const uint4* __restrict__ z1,
                         const uint4* __restrict__ z2,
                         const float* __restrict__ dinv, const float* __restrict__ dinv2,
                         const int* __restrict__ base, const int* __restrict__ col,
                         const int* __restrict__ user, const int* __restrict__ pos,
                         const int* __restrict__ neg,
                         float* __restrict__ lacc, int* __restrict__ done,
                         float* __restrict__ out) {
    __shared__ float s[4];
    int gw   = (blockIdx.x * 256 + threadIdx.x) >> 6;   // batch element (< BATCH by grid)
    int lane = threadIdx.x & 63;
    int sub  = lane & 15;
    int q    = lane >> 4;
    int u = user[gw];
    int p = N_USERS + pos[gw] - 1;   // 1-indexed items
    int n = N_USERS + neg[gw] - 1;
    int node = (q == 1) ? p : (q == 2) ? n : u;
    float vals[8] = {0,0,0,0,0,0,0,0};
    if (q < 3) {
        // z0+z1+z2 at node
        int o = (node << 4) + sub;
        add_u4(vals, z0[o]);
        add_u4(vals, z1[o]);
        add_u4(vals, z2[o]);
        // inline layer-3 gather (f32, no extra rounding)
        int sidx = base[node], eidx = base[node + 1];
        float a0[8] = {0,0,0,0,0,0,0,0};
        float a1[8] = {0,0,0,0,0,0,0,0};
        int j = sidx;
        for (; j + 3 < eidx; j += 4) {
            int c0 = col[j], c1 = col[j + 1], c2 = col[j + 2], c3 = col[j + 3];
            uint4 t0 = z2[(c0 << 4) + sub];
            uint4 t1 = z2[(c1 << 4) + sub];
            uint4 t2 = z2[(c2 << 4) + sub];
            uint4 t3 = z2[(c3 << 4) + sub];
            add_u4(a0, t0); add_u4(a1, t1);
            add_u4(a0, t2); add_u4(a1, t3);
        }
        for (; j < eidx; ++j) {
            uint4 t0 = z2[(col[j] << 4) + sub];
            add_u4(a0, t0);
        }
        float w = dinv2[node];
        #pragma unroll
        for (int k = 0; k < 8; ++k) vals[k] += w * (a0[k] + a1[k]);
    }
    // pull quarter-0 (u-row) values into every quarter: srcLane = sub
    float dotp = 0.0f;
    #pragma unroll
    for (int k = 0; k < 8; ++k) {
        float av = __shfl(vals[k], sub);
        dotp += av * vals[k];
    }
    // reduce within the 16-lane quarter
    #pragma unroll
    for (int off = 8; off; off >>= 1) dotp += __shfl_down(dotp, off, 16);
    float sp = __shfl(dotp, 16);   // quarter 1 sub 0 holds a.b
    float sn = __shfl(dotp, 32);   // quarter 2 sub 0 holds a.c
    if (lane == 0) {
        float du = dinv[u], dp = dinv[p], dn = dinv[n];
        float diff = (sp / (du * dp) - sn / (du * dn)) * (1.0f / 16.0f);
        // log_sigmoid(x) = min(x,0) - log1p(exp(-|x|))
        s[threadIdx.x >> 6] = fminf(diff, 0.0f) - log1pf(expf(-fabsf(diff)));
    }
    __syncthreads();
    if (threadIdx.x == 0) {
        atomicAdd(lacc, s[0] + s[1] + s[2] + s[3]);
        __threadfence();
        int prev = atomicAdd(done, 1);
        if (prev == BPR_BLOCKS - 1) {
            float total = atomicAdd(lacc, 0.0f);   // coherent read at LLC
            out[0] = -total * (1.0f / (float)BATCH);
        }
    }
}

extern "C" void kernel_launch(void* const* d_in, const int* in_sizes, int n_in,
                              void* d_out, int out_size, void* d_ws, size_t ws_size,
                              hipStream_t stream) {
    const float* ue  = (const float*)d_in[0];
    const float* ie  = (const float*)d_in[1];
    const int*   au  = (const int*)d_in[2];
    const int*   ai  = (const int*)d_in[3];
    const int*   usr = (const int*)d_in[4];
    const int*   pos = (const int*)d_in[5];
    const int*   neg = (const int*)d_in[6];
    float*       out = (float*)d_out;

    const size_t XNH = (size_t)NNODES * D / 2;  // uints per bf16 z buffer

    // ws layout (16B-aligned chunks):
    // z0 | z1 | z2 (bf16) | dinv | dinv2 |
    // [cnt | fillc | lacc | done] <- one contiguous memset | base[60008] | col | bsum | boff
    unsigned* z0    = (unsigned*)d_ws;
    unsigned* z1    = z0 + XNH;
    unsigned* z2    = z1 + XNH;
    float*    dinv  = (float*)(z2 + XNH);
    float*    dinv2 = dinv + NNODES;
    int*      cnt   = (int*)(dinv2 + NNODES);
    int*      fillc = cnt + NNODES;
    float*    lacc  = (float*)(fillc + NNODES);
    int*      done  = (int*)(lacc + 1);
    int*      base  = (int*)(lacc + 4);         // keep 16B align
    int*      col   = base + 60008;             // NNODES+1 rounded up
    int*      bsum  = col + NDIR;
    int*      boff  = bsum + 256;

    // cnt + fillc + lacc + done zeroed in one shot
    hipMemsetAsync(cnt, 0, (2 * NNODES + 4) * sizeof(int), stream);

    deg_count<<<(N_EDGES + 255) / 256, 256, 0, stream>>>(au, ai, cnt);
    blk_reduce<<<NBLK, 256, 0, stream>>>(cnt, bsum, dinv, dinv2);
    scan_tops<<<1, 256, 0, stream>>>(bsum, boff);
    blk_scan<<<NBLK, 256, 0, stream>>>(cnt, boff, base);
    fill_and_init<<<FILL_BLOCKS + INIT_BLOCKS, 256, 0, stream>>>(
        au, ai, base, fillc, col, (const float4*)ue, (const float4*)ie,
        dinv, (uint2*)z0);

    const int FULL_BLOCKS = (NNODES + 15) / 16;   // 16 rows per block
    spmm_full<<<FULL_BLOCKS, 256, 0, stream>>>(base, col, dinv2,
                                               (const uint4*)z0, (uint4*)z1);
    spmm_full<<<FULL_BLOCKS, 256, 0, stream>>>(base, col, dinv2,
                                               (const uint4*)z1, (uint4*)z2);

    bpr_loss<<<BPR_BLOCKS, 256, 0, stream>>>((const uint4*)z0, (const uint4*)z1,
                                             (const uint4*)z2, dinv, dinv2, base, col,
                                             usr, pos, neg, lacc, done, out);
}